// Round 21
// baseline (175.276 us; speedup 1.0000x reference)
//
#include <hip/hip_runtime.h>

typedef unsigned short u16;
typedef __attribute__((ext_vector_type(8))) _Float16 f16x8;
typedef __attribute__((ext_vector_type(2))) _Float16 f16x2;
typedef __attribute__((ext_vector_type(4))) float f32x4;
typedef __attribute__((ext_vector_type(4))) unsigned short u16x4;
typedef __attribute__((ext_vector_type(8))) unsigned short u16x8;

#define MFMA16F __builtin_amdgcn_mfma_f32_16x16x32_f16

// barrier that waits LDS ops only — global stores / prefetch loads stay in flight
#define BAR_LDS() do{ asm volatile("s_waitcnt lgkmcnt(0)" ::: "memory"); \
                      __builtin_amdgcn_s_barrier(); }while(0)

#define HW   16384
#define NCLS 150
#define NPAD 160
#define CDIM 256

// LDS strides (shorts)
#define FT_STRIDE 264   // ftF [64 px][256 c]
#define CL_STRIDE 264   // clsL [160 n][256 c] (resident)
#define FN_STRIDE 72    // featN [c][64 px]
#define EP_STRIDE 72    // E'    [160 n][64 px]
#define W_STRIDE  168   // E [64 px][160 n]; clsWT rows
#define CT_STRIDE 264   // combT tile [80 n][256 k]

// kSO1 LDS layout (bytes): 145920 -> 1 block/CU (cls resident)
#define SO_CL   0        // clsL [160][264] u16 = 84480
#define SO_FT   84480    // ftF [64][264] u16 = 33792
#define SO_E    118272   // E [64][168] u16 = 21504
#define SO_ROWM 139776   // [160][4] f32 = 2560
#define SO_ROWS 142336   // [160][4] f32 = 2560
#define SO_PMX  144896   // [2][64] f32 = 512
#define SO_PZS  145408   // [2][64] f32 = 512
#define SO_LDS  145920

// kOut0 LDS (bytes): Ep 23040 + fN-half 18432 = 41472 -> 3 blocks/CU
#define O0_LDS  (NPAD*EP_STRIDE*2 + 128*FN_STRIDE*2)

// workspace offsets (bytes)
#define WS_CLSF  0          // [8][160][256] f16
#define WS_CLSWT 655360     // [8][256][160] f16
#define WS_MG    2359296    // [8][160] f32
#define WS_RZ    2364416    // [8][160] f32
#define WS_WCF   2369536    // [256][256] f16
#define WS_COMBT 2500608    // [8][160][256] f16
#define WS_ROWP  3155968    // [8][256][160][2] f32 (part aliases after kComb)
#define WS_PART  3155968    // [8][32][256][160] f16 (written later by kOut0)
#define WS_S     24127488   // [8][160][16384] f16

__device__ __forceinline__ u16 f2h(float f){ return __builtin_bit_cast(u16, (_Float16)f); }
__device__ __forceinline__ float h2f(u16 h){ return (float)__builtin_bit_cast(_Float16, h); }
__device__ __forceinline__ f16x2 shfl_h2(f16x2 v, int m){
  int x = __builtin_bit_cast(int, v);
  x = __shfl_xor(x, m);
  return __builtin_bit_cast(f16x2, x);
}

// ---------------- k0: cls -> f16 + clsWT = (cls @ Wf^T)^T f16; tail blocks: Wc -> f16
__global__ __launch_bounds__(256) void k0(const float* __restrict__ cls, const float* __restrict__ Wf,
                                          const float* __restrict__ Wc,
                                          u16* __restrict__ clsF, u16* __restrict__ clsWT,
                                          u16* __restrict__ WcF){
  int t = threadIdx.x;
  if (blockIdx.x >= 8*NPAD){
    int i = ((blockIdx.x - 8*NPAD)*256 + t)*4;
    f32x4 v = *(const f32x4*)&Wc[i];
    u16x4 o = {f2h(v[0]), f2h(v[1]), f2h(v[2]), f2h(v[3])};
    *(u16x4*)&WcF[i] = o;
    return;
  }
  int b = blockIdx.x / NPAD, n = blockIdx.x % NPAD;
  __shared__ float row[256];
  int bn = b*NPAD + n;
  if (n < NCLS){
    float v = cls[(b*NCLS + n)*CDIM + t];
    clsF[bn*CDIM + t] = f2h(v);
    row[t] = v;
    __syncthreads();
    float acc = 0.f;
    const float* wr = Wf + t*CDIM;
    #pragma unroll 4
    for (int c = 0; c < 256; c += 4){
      acc += row[c]*wr[c] + row[c+1]*wr[c+1] + row[c+2]*wr[c+2] + row[c+3]*wr[c+3];
    }
    clsWT[(b*CDIM + t)*NPAD + n] = f2h(acc);
  } else {
    clsF[bn*CDIM + t] = 0;
    clsWT[(b*CDIM + t)*NPAD + n] = 0;
  }
}

// ---------------- kSO1 v10: NT on out1 AND S stores; feat loads + part stay cached
// (r19/r20 decomposition: NT feat loads were the downstream killer, not NT S).
__global__ __launch_bounds__(512) void kSO1(const float* __restrict__ feat,
                                            const u16* __restrict__ clsF,
                                            const u16* __restrict__ clsWT,
                                            u16* __restrict__ Sg, float* __restrict__ rowP,
                                            float* __restrict__ out1){
  extern __shared__ char sm[];
  u16*  clsL = (u16*)(sm + SO_CL);
  u16*  ftF  = (u16*)(sm + SO_FT);
  u16*  E    = (u16*)(sm + SO_E);
  float* rowM = (float*)(sm + SO_ROWM);
  float* rowS = (float*)(sm + SO_ROWS);
  float* pmx  = (float*)(sm + SO_PMX);
  float* pzs  = (float*)(sm + SO_PZS);

  int b = blockIdx.x & 7, ch = blockIdx.x >> 3, t = threadIdx.x;
  const float* featG = feat + (size_t)b*CDIM*HW;
  const u16* clsB  = clsF  + b*NPAD*CDIM;
  const u16* clsWB = clsWT + b*CDIM*NPAD;
  u16* Sb = Sg + (size_t)b*NPAD*HW;

  int lane = t & 63, wv = t >> 6;
  int l15 = lane & 15, lk = (lane >> 4) & 3;
  int nh = wv >> 2, pq = wv & 3;
  int nbase = nh*80;
  int col = pq*16 + l15;
  int cstrip = wv*32;
  int p = t & 63, cg = t >> 6;

  // ---- prologue (once per CU): stage clsL, preload clsWT frags, load tile-0 feat
  #pragma unroll
  for (int it = 0; it < 10; ++it){
    int idx8 = (it*512 + t)*8;
    int n = idx8 >> 8, c = idx8 & 255;
    u16x8 v = *(const u16x8*)&clsB[idx8];
    *(u16x8*)&clsL[n*CL_STRIDE + c] = v;
  }
  f16x8 aw0[5], aw1[5];
  #pragma unroll
  for (int kb = 0; kb < 5; ++kb){
    aw0[kb] = *(const f16x8*)&clsWB[(cstrip + l15)*NPAD + kb*32 + lk*8];
    aw1[kb] = *(const f16x8*)&clsWB[(cstrip + 16 + l15)*NPAD + kb*32 + lk*8];
  }
  #pragma unroll
  for (int kb = 0; kb < 5; ++kb){
    asm volatile("" :: "v"(aw0[kb]), "v"(aw1[kb]));
  }
  f32x4 pf[8];
  {
    int p00 = ch*512;
    #pragma unroll
    for (int i = 0; i < 8; ++i){
      int c0 = (i*8 + cg)*4;
      const float* g0 = featG + (size_t)c0*HW + p00 + p;
      pf[i][0] = g0[0]; pf[i][1] = g0[HW]; pf[i][2] = g0[2*HW]; pf[i][3] = g0[3*HW];
    }
  }

  for (int tl = 0; tl < 8; ++tl){
    int p0 = ch*512 + tl*64;
    BAR_LDS();   // B_a: prior tile's LDS readers done (iter0: clsL writes done)
    // ---- ds_write ftF from prefetched regs; issue next tile's loads
    #pragma unroll
    for (int i = 0; i < 8; ++i){
      int c0 = (i*8 + cg)*4;
      u16x4 hv = {f2h(pf[i][0]), f2h(pf[i][1]), f2h(pf[i][2]), f2h(pf[i][3])};
      *(u16x4*)&ftF[p*FT_STRIDE + c0] = hv;
    }
    if (tl < 7){
      int p0n = p0 + 64;
      #pragma unroll
      for (int i = 0; i < 8; ++i){
        int c0 = (i*8 + cg)*4;
        const float* g0 = featG + (size_t)c0*HW + p0n + p;
        pf[i][0] = g0[0]; pf[i][1] = g0[HW]; pf[i][2] = g0[2*HW]; pf[i][3] = g0[3*HW];
      }
    }
    BAR_LDS();   // B_b: ftF ready
    // ---- S-GEMM: straight 40 MFMA, clsL resident
    f32x4 acc[5];
    #pragma unroll
    for (int f = 0; f < 5; ++f) acc[f] = (f32x4){0.f,0.f,0.f,0.f};
    __builtin_amdgcn_s_setprio(1);
    #pragma unroll
    for (int kb = 0; kb < 8; ++kb){
      int ko = kb*32 + lk*8;
      f16x8 bh = *(const f16x8*)&ftF[(pq*16 + l15)*FT_STRIDE + ko];
      #pragma unroll
      for (int f = 0; f < 5; ++f){
        f16x8 ah = *(const f16x8*)&clsL[(nbase + f*16 + l15)*CL_STRIDE + ko];
        acc[f] = MFMA16F(ah, bh, acc[f], 0, 0, 0);
      }
    }
    __builtin_amdgcn_s_setprio(0);
    // ---- write S to global (NT: relieve L2 store drain; kOut0 reads from HBM/L3)
    #pragma unroll
    for (int f = 0; f < 5; ++f){
      #pragma unroll
      for (int r = 0; r < 4; ++r){
        int n = nbase + f*16 + 4*lk + r;
        __builtin_nontemporal_store(f2h(acc[f][r]), &Sb[(size_t)n*HW + p0 + col]);
      }
    }
    // ---- row (cls) stats: packed-f16 butterflies
    #pragma unroll
    for (int f = 0; f < 5; ++f){
      #pragma unroll
      for (int rp = 0; rp < 2; ++rp){
        float v0 = acc[f][rp*2], v1 = acc[f][rp*2 + 1];
        f16x2 pm_ = {(_Float16)v0, (_Float16)v1};
        pm_ = __builtin_elementwise_max(pm_, shfl_h2(pm_, 1));
        pm_ = __builtin_elementwise_max(pm_, shfl_h2(pm_, 2));
        pm_ = __builtin_elementwise_max(pm_, shfl_h2(pm_, 4));
        pm_ = __builtin_elementwise_max(pm_, shfl_h2(pm_, 8));
        float m0 = (float)pm_[0], m1 = (float)pm_[1];
        f16x2 ps_ = {(_Float16)__expf(v0 - m0), (_Float16)__expf(v1 - m1)};
        ps_ = ps_ + shfl_h2(ps_, 1);
        ps_ = ps_ + shfl_h2(ps_, 2);
        ps_ = ps_ + shfl_h2(ps_, 4);
        ps_ = ps_ + shfl_h2(ps_, 8);
        if (l15 == f){
          int n0 = nbase + f*16 + 4*lk + rp*2;
          rowM[n0*4 + pq]       = m0;
          rowM[(n0 + 1)*4 + pq] = m1;
          rowS[n0*4 + pq]       = (float)ps_[0];
          rowS[(n0 + 1)*4 + pq] = (float)ps_[1];
        }
      }
    }
    // ---- pixel (pos) max: in-lane + shfl over lk
    {
      float pmax = -3.0e38f;
      #pragma unroll
      for (int f = 0; f < 5; ++f)
        #pragma unroll
        for (int r = 0; r < 4; ++r){
          int n = nbase + 16*f + 4*lk + r;
          if (n < NCLS) pmax = fmaxf(pmax, acc[f][r]);
        }
      pmax = fmaxf(pmax, __shfl_xor(pmax, 16));
      pmax = fmaxf(pmax, __shfl_xor(pmax, 32));
      if (lk == 0) pmx[nh*64 + col] = pmax;
    }
    BAR_LDS();   // B_c: pmx + rowM/rowS ready
    // ---- combine row stats -> rowP (t<160)
    if (t < NPAD){
      float rm0 = rowM[t*4+0], rm1 = rowM[t*4+1], rm2 = rowM[t*4+2], rm3 = rowM[t*4+3];
      float msub = fmaxf(fmaxf(rm0, rm1), fmaxf(rm2, rm3));
      float l = rowS[t*4+0]*__expf(rm0 - msub) + rowS[t*4+1]*__expf(rm1 - msub)
              + rowS[t*4+2]*__expf(rm2 - msub) + rowS[t*4+3]*__expf(rm3 - msub);
      float* rp = rowP + ((size_t)(b*256 + ch*8 + tl)*NPAD + t)*2;
      rp[0] = msub;
      rp[1] = l;
    }
    // ---- exp in-register, write E^T (exponentiated), z-reduce -> pzs
    {
      float mp_ = fmaxf(pmx[col], pmx[64 + col]);
      float s = 0.f;
      #pragma unroll
      for (int f = 0; f < 5; ++f){
        u16x4 ev;
        #pragma unroll
        for (int r = 0; r < 4; ++r){
          int n = nbase + 16*f + 4*lk + r;
          float e = (n < NCLS) ? __expf(acc[f][r] - mp_) : 0.f;
          s += e;
          ev[r] = f2h(e);
        }
        *(u16x4*)&E[col*W_STRIDE + nbase + 16*f + 4*lk] = ev;
      }
      s += __shfl_xor(s, 16);
      s += __shfl_xor(s, 32);
      if (lk == 0) pzs[nh*64 + col] = s;
    }
    BAR_LDS();   // B_d: E(exp) + pzs ready
    // ---- out1-GEMM
    f32x4 accO[2][4];
    #pragma unroll
    for (int cf = 0; cf < 2; ++cf)
      #pragma unroll
      for (int pfi = 0; pfi < 4; ++pfi) accO[cf][pfi] = (f32x4){0.f,0.f,0.f,0.f};
    __builtin_amdgcn_s_setprio(1);
    #pragma unroll
    for (int kb = 0; kb < 5; ++kb){
      int ko = kb*32 + lk*8;
      #pragma unroll
      for (int pfi = 0; pfi < 4; ++pfi){
        f16x8 bb = *(const f16x8*)&E[(pfi*16 + l15)*W_STRIDE + ko];
        accO[0][pfi] = MFMA16F(aw0[kb], bb, accO[0][pfi], 0, 0, 0);
        accO[1][pfi] = MFMA16F(aw1[kb], bb, accO[1][pfi], 0, 0, 0);
      }
    }
    __builtin_amdgcn_s_setprio(0);
    // ---- epilogue: rz per-lane from pzs (stable since B_d); NT stores to out1 (final output)
    float rz4[4];
    #pragma unroll
    for (int pfi = 0; pfi < 4; ++pfi){
      int pp = pfi*16 + l15;
      rz4[pfi] = 1.0f / (pzs[pp] + pzs[64 + pp]);
    }
    #pragma unroll
    for (int cf = 0; cf < 2; ++cf){
      #pragma unroll
      for (int r = 0; r < 4; ++r){
        int c = cstrip + cf*16 + lk*4 + r;
        float* ob = out1 + (size_t)(b*CDIM + c)*HW + p0;
        #pragma unroll
        for (int pfi = 0; pfi < 4; ++pfi){
          int pp = pfi*16 + l15;
          __builtin_nontemporal_store(accO[cf][pfi][r]*rz4[pfi] + h2f(ftF[pp*FT_STRIDE + c]), &ob[pp]);
        }
      }
    }
  }
}

// ---------------- kComb: reduce 256 tile row-partials -> m_g, rZ (2-level)
__global__ __launch_bounds__(256) void kComb(const float* __restrict__ rowP,
                                             float* __restrict__ mg, float* __restrict__ rz){
  int b = blockIdx.x / 10, nb = blockIdx.x % 10, t = threadIdx.x;
  int sg = t >> 4, j = t & 15;
  int n = nb*16 + j;
  __shared__ float pm[16][17], pl[16][17];
  float m = -3.0e38f, l = 0.f;
  for (int i = 0; i < 16; ++i){
    int s = sg*16 + i;
    const float* rp = rowP + ((size_t)(b*256 + s)*NPAD + n)*2;
    float ms = rp[0], ls = rp[1];
    float mn = fmaxf(m, ms);
    l = l*__expf(m - mn) + ls*__expf(ms - mn);
    m = mn;
  }
  pm[sg][j] = m;
  pl[sg][j] = l;
  __syncthreads();
  if (sg == 0){
    float M = pm[0][j], L = pl[0][j];
    #pragma unroll
    for (int k = 1; k < 16; ++k){
      float ms = pm[k][j], ls = pl[k][j];
      float mn = fmaxf(M, ms);
      L = L*__expf(M - mn) + ls*__expf(ms - mn);
      M = mn;
    }
    mg[b*NPAD + n] = M;
    rz[b*NPAD + n] = 1.0f / L;
  }
}

// ---------------- kOut0: c-split (512 blocks, 3/CU), cached loads/stores
__global__ __launch_bounds__(512) void kOut0(const u16* __restrict__ Sg, const float* __restrict__ feat,
                                             const float* __restrict__ mg, u16* __restrict__ part){
  extern __shared__ char sm[];
  u16* Ep = (u16*)sm;                        // [NPAD][EP_STRIDE]
  u16* fN = (u16*)(sm + NPAD*EP_STRIDE*2);   // [128][FN_STRIDE]
  int b = blockIdx.x & 7, pr = (blockIdx.x >> 3) & 31, ch = (blockIdx.x >> 8) & 1;
  int t = threadIdx.x;
  const u16* Sb = Sg + (size_t)b*NPAD*HW;
  const float* featB = feat + (size_t)b*CDIM*HW;
  const float* mgB = mg + b*NPAD;
  int lane = t & 63, wv = t >> 6;
  int l15 = lane & 15, lk = (lane >> 4) & 3;
  int cstrip = wv*16;
  int rr = t >> 3, px8 = (t & 7)*8;
  f32x4 acc[10];
  #pragma unroll
  for (int nf = 0; nf < 10; ++nf) acc[nf] = (f32x4){0.f,0.f,0.f,0.f};
  for (int ck = 0; ck < 8; ++ck){
    int p0 = pr*512 + ck*64;
    #pragma unroll
    for (int ps = 0; ps < 3; ++ps){
      int rowi = ps*64 + rr;
      if (rowi < NPAD){
        u16x8 v = *(const u16x8*)&Sb[(size_t)rowi*HW + p0 + px8];
        float m = mgB[rowi];
        u16x8 o;
        #pragma unroll
        for (int j = 0; j < 8; ++j) o[j] = f2h(__expf(h2f(v[j]) - m));
        *(u16x8*)&Ep[rowi*EP_STRIDE + px8] = o;
      }
    }
    #pragma unroll
    for (int ps = 0; ps < 2; ++ps){
      int cl = ps*64 + rr;
      const float* g = featB + (size_t)(ch*128 + cl)*HW + p0 + px8;
      f32x4 v0 = *(const f32x4*)&g[0];
      f32x4 v1 = *(const f32x4*)&g[4];
      u16x8 o = {f2h(v0[0]), f2h(v0[1]), f2h(v0[2]), f2h(v0[3]),
                 f2h(v1[0]), f2h(v1[1]), f2h(v1[2]), f2h(v1[3])};
      *(u16x8*)&fN[cl*FN_STRIDE + px8] = o;
    }
    BAR_LDS();
    __builtin_amdgcn_s_setprio(1);
    #pragma unroll
    for (int kb = 0; kb < 2; ++kb){
      int ko = kb*32 + lk*8;
      f16x8 a0 = *(const f16x8*)&fN[(cstrip + l15)*FN_STRIDE + ko];
      #pragma unroll
      for (int nf = 0; nf < 10; ++nf){
        f16x8 bb = *(const f16x8*)&Ep[(nf*16 + l15)*EP_STRIDE + ko];
        acc[nf] = MFMA16F(a0, bb, acc[nf], 0, 0, 0);
      }
    }
    __builtin_amdgcn_s_setprio(0);
    BAR_LDS();
  }
  #pragma unroll
  for (int nf = 0; nf < 10; ++nf){
    #pragma unroll
    for (int r = 0; r < 4; ++r){
      int c = ch*128 + cstrip + lk*4 + r;
      int n = nf*16 + l15;
      part[((size_t)(b*32 + pr)*CDIM + c)*NPAD + n] = f2h(acc[nf][r]);
    }
  }
}

// ---------------- k4a: streaming reduce of part over 32 chunks, fold rZ -> combT
__global__ __launch_bounds__(256) void k4a(const u16* __restrict__ part, const float* __restrict__ rz,
                                           u16* __restrict__ combT){
  int b = blockIdx.x / 20, sub = blockIdx.x % 20, t = threadIdx.x;
  int idx8 = (sub*256 + t)*8;
  int c = idx8 / NPAD, n0 = idx8 % NPAD;
  const u16* base = part + (size_t)(b*32)*CDIM*NPAD + idx8;
  float a[8];
  #pragma unroll
  for (int j = 0; j < 8; ++j) a[j] = 0.f;
  for (int s = 0; s < 32; ++s){
    u16x8 v = *(const u16x8*)&base[(size_t)s*CDIM*NPAD];
    #pragma unroll
    for (int j = 0; j < 8; ++j) a[j] += h2f(v[j]);
  }
  const float* rzB = rz + b*NPAD + n0;
  #pragma unroll
  for (int j = 0; j < 8; ++j){
    combT[((size_t)(b*NPAD) + n0 + j)*CDIM + c] = f2h(a[j] * rzB[j]);
  }
}

// ---------------- k4b: out0[n][c] = cls + combT[n][:] @ WcF[c][:]  (MFMA, 80 n-rows/block)
__global__ __launch_bounds__(512) void k4b(const u16* __restrict__ combT, const u16* __restrict__ WcF,
                                           const float* __restrict__ cls, float* __restrict__ out0){
  extern __shared__ char sm[];
  u16* A = (u16*)sm;   // [80][CT_STRIDE]
  int b = blockIdx.x >> 1, nb = blockIdx.x & 1, t = threadIdx.x;
  const u16* cb = combT + (size_t)(b*NPAD + nb*80)*CDIM;
  #pragma unroll
  for (int it = 0; it < 10; ++it){
    int idx8 = (it*512 + t)*8;
    if (idx8 < 80*256){
      int row = idx8 >> 8, k0 = idx8 & 255;
      u16x8 v = *(const u16x8*)&cb[idx8];
      *(u16x8*)&A[row*CT_STRIDE + k0] = v;
    }
  }
  __syncthreads();
  int lane = t & 63, wv = t >> 6;
  int l15 = lane & 15, lk = (lane >> 4) & 3;
  int cstrip = wv*32;
  f32x4 acc[5][2];
  #pragma unroll
  for (int f = 0; f < 5; ++f)
    #pragma unroll
    for (int ct = 0; ct < 2; ++ct) acc[f][ct] = (f32x4){0.f,0.f,0.f,0.f};
  #pragma unroll
  for (int kb = 0; kb < 8; ++kb){
    int ko = kb*32 + lk*8;
    f16x8 b0 = *(const f16x8*)&WcF[(cstrip + l15)*CDIM + ko];
    f16x8 b1 = *(const f16x8*)&WcF[(cstrip + 16 + l15)*CDIM + ko];
    #pragma unroll
    for (int f = 0; f < 5; ++f){
      f16x8 af = *(const f16x8*)&A[(f*16 + l15)*CT_STRIDE + ko];
      acc[f][0] = MFMA16F(af, b0, acc[f][0], 0, 0, 0);
      acc[f][1] = MFMA16F(af, b1, acc[f][1], 0, 0, 0);
    }
  }
  #pragma unroll
  for (int f = 0; f < 5; ++f){
    #pragma unroll
    for (int r = 0; r < 4; ++r){
      int n = nb*80 + f*16 + lk*4 + r;
      if (n < NCLS){
        #pragma unroll
        for (int ct = 0; ct < 2; ++ct){
          int c = cstrip + ct*16 + l15;
          __builtin_nontemporal_store(cls[(size_t)(b*NCLS + n)*CDIM + c] + acc[f][ct][r],
                                      &out0[(size_t)(b*NCLS + n)*CDIM + c]);
        }
      }
    }
  }
}

extern "C" void kernel_launch(void* const* d_in, const int* in_sizes, int n_in,
                              void* d_out, int out_size, void* d_ws, size_t ws_size,
                              hipStream_t stream){
  (void)in_sizes; (void)n_in; (void)out_size; (void)ws_size;
  const float* cls  = (const float*)d_in[0];   // [8][150][256]
  const float* feat = (const float*)d_in[1];   // [8][256][16384]
  const float* Wc   = (const float*)d_in[2];   // [256][256]
  const float* Wf   = (const float*)d_in[3];   // [256][256]
  float* out0 = (float*)d_out;                 // [8][150][256]
  float* out1 = out0 + 8*NCLS*CDIM;            // [8][256][16384]
  char* ws = (char*)d_ws;
  u16*   clsF   = (u16*)(ws + WS_CLSF);
  u16*   clsWT  = (u16*)(ws + WS_CLSWT);
  float* mgv    = (float*)(ws + WS_MG);
  float* rzv    = (float*)(ws + WS_RZ);
  u16*   WcFv   = (u16*)(ws + WS_WCF);
  u16*   combTv = (u16*)(ws + WS_COMBT);
  float* rowPv  = (float*)(ws + WS_ROWP);
  u16*   partv  = (u16*)(ws + WS_PART);
  u16*   Sgp    = (u16*)(ws + WS_S);

  (void)hipFuncSetAttribute((const void*)kSO1, hipFuncAttributeMaxDynamicSharedMemorySize, SO_LDS);

  k0   <<<8*NPAD + 64, 256, 0, stream>>>(cls, Wf, Wc, clsF, clsWT, WcFv);
  kSO1 <<<256, 512, SO_LDS, stream>>>(feat, clsF, clsWT, Sgp, rowPv, out1);
  kComb<<<80, 256, 0, stream>>>(rowPv, mgv, rzv);
  kOut0<<<512, 512, O0_LDS, stream>>>(Sgp, feat, mgv, partv);
  k4a  <<<160, 256, 0, stream>>>(partv, rzv, combTv);
  k4b  <<<16, 512, 80*CT_STRIDE*2, stream>>>(combTv, WcFv, cls, out0);
}

// Round 22
// 171.529 us; speedup vs baseline: 1.0218x; 1.0218x over previous
//
#include <hip/hip_runtime.h>

typedef unsigned short u16;
typedef __attribute__((ext_vector_type(8))) _Float16 f16x8;
typedef __attribute__((ext_vector_type(2))) _Float16 f16x2;
typedef __attribute__((ext_vector_type(4))) float f32x4;
typedef __attribute__((ext_vector_type(4))) unsigned short u16x4;
typedef __attribute__((ext_vector_type(8))) unsigned short u16x8;

#define MFMA16F __builtin_amdgcn_mfma_f32_16x16x32_f16

// barrier that waits LDS ops only — global stores / prefetch loads stay in flight
#define BAR_LDS() do{ asm volatile("s_waitcnt lgkmcnt(0)" ::: "memory"); \
                      __builtin_amdgcn_s_barrier(); }while(0)

#define HW   16384
#define NCLS 150
#define NPAD 160
#define CDIM 256

// LDS strides (shorts)
#define FT_STRIDE 264   // ftF [64 px][256 c]
#define CL_STRIDE 264   // clsL [160 n][256 c] (resident)
#define FN_STRIDE 72    // featN [c][64 px]
#define EP_STRIDE 72    // E'    [160 n][64 px]
#define W_STRIDE  168   // E [64 px][160 n]; clsWT rows
#define CT_STRIDE 264   // combT tile [80 n][256 k]

// kSO1 LDS layout (bytes): 145920 -> 1 block/CU (cls resident)
#define SO_CL   0        // clsL [160][264] u16 = 84480
#define SO_FT   84480    // ftF [64][264] u16 = 33792
#define SO_E    118272   // E [64][168] u16 = 21504
#define SO_ROWM 139776   // [160][4] f32 = 2560
#define SO_ROWS 142336   // [160][4] f32 = 2560
#define SO_PMX  144896   // [2][64] f32 = 512
#define SO_PZS  145408   // [2][64] f32 = 512
#define SO_LDS  145920

// kOut0 LDS (bytes): Ep 23040 + fN-half 18432 = 41472 -> 3 blocks/CU
#define O0_LDS  (NPAD*EP_STRIDE*2 + 128*FN_STRIDE*2)

// workspace offsets (bytes)
#define WS_CLSF  0          // [8][160][256] f16
#define WS_CLSWT 655360     // [8][256][160] f16
#define WS_MG    2359296    // [8][160] f32
#define WS_RZ    2364416    // [8][160] f32
#define WS_WCF   2369536    // [256][256] f16
#define WS_COMBT 2500608    // [8][160][256] f16
#define WS_ROWP  3155968    // [8][256][160][2] f32 (part aliases after kComb)
#define WS_PART  3155968    // [8][32][256][160] f16 (written later by kOut0)
#define WS_S     24127488   // [8][160][16384] f16

__device__ __forceinline__ u16 f2h(float f){ return __builtin_bit_cast(u16, (_Float16)f); }
__device__ __forceinline__ float h2f(u16 h){ return (float)__builtin_bit_cast(_Float16, h); }
__device__ __forceinline__ f16x2 shfl_h2(f16x2 v, int m){
  int x = __builtin_bit_cast(int, v);
  x = __shfl_xor(x, m);
  return __builtin_bit_cast(f16x2, x);
}

// ---------------- k0: cls -> f16 + clsWT = (cls @ Wf^T)^T f16; tail blocks: Wc -> f16
__global__ __launch_bounds__(256) void k0(const float* __restrict__ cls, const float* __restrict__ Wf,
                                          const float* __restrict__ Wc,
                                          u16* __restrict__ clsF, u16* __restrict__ clsWT,
                                          u16* __restrict__ WcF){
  int t = threadIdx.x;
  if (blockIdx.x >= 8*NPAD){
    int i = ((blockIdx.x - 8*NPAD)*256 + t)*4;
    f32x4 v = *(const f32x4*)&Wc[i];
    u16x4 o = {f2h(v[0]), f2h(v[1]), f2h(v[2]), f2h(v[3])};
    *(u16x4*)&WcF[i] = o;
    return;
  }
  int b = blockIdx.x / NPAD, n = blockIdx.x % NPAD;
  __shared__ float row[256];
  int bn = b*NPAD + n;
  if (n < NCLS){
    float v = cls[(b*NCLS + n)*CDIM + t];
    clsF[bn*CDIM + t] = f2h(v);
    row[t] = v;
    __syncthreads();
    float acc = 0.f;
    const float* wr = Wf + t*CDIM;
    #pragma unroll 4
    for (int c = 0; c < 256; c += 4){
      acc += row[c]*wr[c] + row[c+1]*wr[c+1] + row[c+2]*wr[c+2] + row[c+3]*wr[c+3];
    }
    clsWT[(b*CDIM + t)*NPAD + n] = f2h(acc);
  } else {
    clsF[bn*CDIM + t] = 0;
    clsWT[(b*CDIM + t)*NPAD + n] = 0;
  }
}

// ---------------- kSO1 (final, r20 config): NT ONLY on out1 (no consumer).
// S stores, part, feat loads cached (r19/r21: NT on consumed tensors is net-negative).
__global__ __launch_bounds__(512) void kSO1(const float* __restrict__ feat,
                                            const u16* __restrict__ clsF,
                                            const u16* __restrict__ clsWT,
                                            u16* __restrict__ Sg, float* __restrict__ rowP,
                                            float* __restrict__ out1){
  extern __shared__ char sm[];
  u16*  clsL = (u16*)(sm + SO_CL);
  u16*  ftF  = (u16*)(sm + SO_FT);
  u16*  E    = (u16*)(sm + SO_E);
  float* rowM = (float*)(sm + SO_ROWM);
  float* rowS = (float*)(sm + SO_ROWS);
  float* pmx  = (float*)(sm + SO_PMX);
  float* pzs  = (float*)(sm + SO_PZS);

  int b = blockIdx.x & 7, ch = blockIdx.x >> 3, t = threadIdx.x;
  const float* featG = feat + (size_t)b*CDIM*HW;
  const u16* clsB  = clsF  + b*NPAD*CDIM;
  const u16* clsWB = clsWT + b*CDIM*NPAD;
  u16* Sb = Sg + (size_t)b*NPAD*HW;

  int lane = t & 63, wv = t >> 6;
  int l15 = lane & 15, lk = (lane >> 4) & 3;
  int nh = wv >> 2, pq = wv & 3;
  int nbase = nh*80;
  int col = pq*16 + l15;
  int cstrip = wv*32;
  int p = t & 63, cg = t >> 6;

  // ---- prologue (once per CU): stage clsL, preload clsWT frags, load tile-0 feat
  #pragma unroll
  for (int it = 0; it < 10; ++it){
    int idx8 = (it*512 + t)*8;
    int n = idx8 >> 8, c = idx8 & 255;
    u16x8 v = *(const u16x8*)&clsB[idx8];
    *(u16x8*)&clsL[n*CL_STRIDE + c] = v;
  }
  f16x8 aw0[5], aw1[5];
  #pragma unroll
  for (int kb = 0; kb < 5; ++kb){
    aw0[kb] = *(const f16x8*)&clsWB[(cstrip + l15)*NPAD + kb*32 + lk*8];
    aw1[kb] = *(const f16x8*)&clsWB[(cstrip + 16 + l15)*NPAD + kb*32 + lk*8];
  }
  #pragma unroll
  for (int kb = 0; kb < 5; ++kb){
    asm volatile("" :: "v"(aw0[kb]), "v"(aw1[kb]));
  }
  f32x4 pf[8];
  {
    int p00 = ch*512;
    #pragma unroll
    for (int i = 0; i < 8; ++i){
      int c0 = (i*8 + cg)*4;
      const float* g0 = featG + (size_t)c0*HW + p00 + p;
      pf[i][0] = g0[0]; pf[i][1] = g0[HW]; pf[i][2] = g0[2*HW]; pf[i][3] = g0[3*HW];
    }
  }

  for (int tl = 0; tl < 8; ++tl){
    int p0 = ch*512 + tl*64;
    BAR_LDS();   // B_a: prior tile's LDS readers done (iter0: clsL writes done)
    // ---- ds_write ftF from prefetched regs; issue next tile's loads
    #pragma unroll
    for (int i = 0; i < 8; ++i){
      int c0 = (i*8 + cg)*4;
      u16x4 hv = {f2h(pf[i][0]), f2h(pf[i][1]), f2h(pf[i][2]), f2h(pf[i][3])};
      *(u16x4*)&ftF[p*FT_STRIDE + c0] = hv;
    }
    if (tl < 7){
      int p0n = p0 + 64;
      #pragma unroll
      for (int i = 0; i < 8; ++i){
        int c0 = (i*8 + cg)*4;
        const float* g0 = featG + (size_t)c0*HW + p0n + p;
        pf[i][0] = g0[0]; pf[i][1] = g0[HW]; pf[i][2] = g0[2*HW]; pf[i][3] = g0[3*HW];
      }
    }
    BAR_LDS();   // B_b: ftF ready
    // ---- S-GEMM: straight 40 MFMA, clsL resident
    f32x4 acc[5];
    #pragma unroll
    for (int f = 0; f < 5; ++f) acc[f] = (f32x4){0.f,0.f,0.f,0.f};
    __builtin_amdgcn_s_setprio(1);
    #pragma unroll
    for (int kb = 0; kb < 8; ++kb){
      int ko = kb*32 + lk*8;
      f16x8 bh = *(const f16x8*)&ftF[(pq*16 + l15)*FT_STRIDE + ko];
      #pragma unroll
      for (int f = 0; f < 5; ++f){
        f16x8 ah = *(const f16x8*)&clsL[(nbase + f*16 + l15)*CL_STRIDE + ko];
        acc[f] = MFMA16F(ah, bh, acc[f], 0, 0, 0);
      }
    }
    __builtin_amdgcn_s_setprio(0);
    // ---- write S to global (cached: kOut0 consumes it)
    #pragma unroll
    for (int f = 0; f < 5; ++f){
      #pragma unroll
      for (int r = 0; r < 4; ++r){
        int n = nbase + f*16 + 4*lk + r;
        Sb[(size_t)n*HW + p0 + col] = f2h(acc[f][r]);
      }
    }
    // ---- row (cls) stats: packed-f16 butterflies
    #pragma unroll
    for (int f = 0; f < 5; ++f){
      #pragma unroll
      for (int rp = 0; rp < 2; ++rp){
        float v0 = acc[f][rp*2], v1 = acc[f][rp*2 + 1];
        f16x2 pm_ = {(_Float16)v0, (_Float16)v1};
        pm_ = __builtin_elementwise_max(pm_, shfl_h2(pm_, 1));
        pm_ = __builtin_elementwise_max(pm_, shfl_h2(pm_, 2));
        pm_ = __builtin_elementwise_max(pm_, shfl_h2(pm_, 4));
        pm_ = __builtin_elementwise_max(pm_, shfl_h2(pm_, 8));
        float m0 = (float)pm_[0], m1 = (float)pm_[1];
        f16x2 ps_ = {(_Float16)__expf(v0 - m0), (_Float16)__expf(v1 - m1)};
        ps_ = ps_ + shfl_h2(ps_, 1);
        ps_ = ps_ + shfl_h2(ps_, 2);
        ps_ = ps_ + shfl_h2(ps_, 4);
        ps_ = ps_ + shfl_h2(ps_, 8);
        if (l15 == f){
          int n0 = nbase + f*16 + 4*lk + rp*2;
          rowM[n0*4 + pq]       = m0;
          rowM[(n0 + 1)*4 + pq] = m1;
          rowS[n0*4 + pq]       = (float)ps_[0];
          rowS[(n0 + 1)*4 + pq] = (float)ps_[1];
        }
      }
    }
    // ---- pixel (pos) max: in-lane + shfl over lk
    {
      float pmax = -3.0e38f;
      #pragma unroll
      for (int f = 0; f < 5; ++f)
        #pragma unroll
        for (int r = 0; r < 4; ++r){
          int n = nbase + 16*f + 4*lk + r;
          if (n < NCLS) pmax = fmaxf(pmax, acc[f][r]);
        }
      pmax = fmaxf(pmax, __shfl_xor(pmax, 16));
      pmax = fmaxf(pmax, __shfl_xor(pmax, 32));
      if (lk == 0) pmx[nh*64 + col] = pmax;
    }
    BAR_LDS();   // B_c: pmx + rowM/rowS ready
    // ---- combine row stats -> rowP (t<160)
    if (t < NPAD){
      float rm0 = rowM[t*4+0], rm1 = rowM[t*4+1], rm2 = rowM[t*4+2], rm3 = rowM[t*4+3];
      float msub = fmaxf(fmaxf(rm0, rm1), fmaxf(rm2, rm3));
      float l = rowS[t*4+0]*__expf(rm0 - msub) + rowS[t*4+1]*__expf(rm1 - msub)
              + rowS[t*4+2]*__expf(rm2 - msub) + rowS[t*4+3]*__expf(rm3 - msub);
      float* rp = rowP + ((size_t)(b*256 + ch*8 + tl)*NPAD + t)*2;
      rp[0] = msub;
      rp[1] = l;
    }
    // ---- exp in-register, write E^T (exponentiated), z-reduce -> pzs
    {
      float mp_ = fmaxf(pmx[col], pmx[64 + col]);
      float s = 0.f;
      #pragma unroll
      for (int f = 0; f < 5; ++f){
        u16x4 ev;
        #pragma unroll
        for (int r = 0; r < 4; ++r){
          int n = nbase + 16*f + 4*lk + r;
          float e = (n < NCLS) ? __expf(acc[f][r] - mp_) : 0.f;
          s += e;
          ev[r] = f2h(e);
        }
        *(u16x4*)&E[col*W_STRIDE + nbase + 16*f + 4*lk] = ev;
      }
      s += __shfl_xor(s, 16);
      s += __shfl_xor(s, 32);
      if (lk == 0) pzs[nh*64 + col] = s;
    }
    BAR_LDS();   // B_d: E(exp) + pzs ready
    // ---- out1-GEMM
    f32x4 accO[2][4];
    #pragma unroll
    for (int cf = 0; cf < 2; ++cf)
      #pragma unroll
      for (int pfi = 0; pfi < 4; ++pfi) accO[cf][pfi] = (f32x4){0.f,0.f,0.f,0.f};
    __builtin_amdgcn_s_setprio(1);
    #pragma unroll
    for (int kb = 0; kb < 5; ++kb){
      int ko = kb*32 + lk*8;
      #pragma unroll
      for (int pfi = 0; pfi < 4; ++pfi){
        f16x8 bb = *(const f16x8*)&E[(pfi*16 + l15)*W_STRIDE + ko];
        accO[0][pfi] = MFMA16F(aw0[kb], bb, accO[0][pfi], 0, 0, 0);
        accO[1][pfi] = MFMA16F(aw1[kb], bb, accO[1][pfi], 0, 0, 0);
      }
    }
    __builtin_amdgcn_s_setprio(0);
    // ---- epilogue: rz per-lane from pzs (stable since B_d); NT stores to out1 (final output)
    float rz4[4];
    #pragma unroll
    for (int pfi = 0; pfi < 4; ++pfi){
      int pp = pfi*16 + l15;
      rz4[pfi] = 1.0f / (pzs[pp] + pzs[64 + pp]);
    }
    #pragma unroll
    for (int cf = 0; cf < 2; ++cf){
      #pragma unroll
      for (int r = 0; r < 4; ++r){
        int c = cstrip + cf*16 + lk*4 + r;
        float* ob = out1 + (size_t)(b*CDIM + c)*HW + p0;
        #pragma unroll
        for (int pfi = 0; pfi < 4; ++pfi){
          int pp = pfi*16 + l15;
          __builtin_nontemporal_store(accO[cf][pfi][r]*rz4[pfi] + h2f(ftF[pp*FT_STRIDE + c]), &ob[pp]);
        }
      }
    }
  }
}

// ---------------- kComb: reduce 256 tile row-partials -> m_g, rZ (2-level)
__global__ __launch_bounds__(256) void kComb(const float* __restrict__ rowP,
                                             float* __restrict__ mg, float* __restrict__ rz){
  int b = blockIdx.x / 10, nb = blockIdx.x % 10, t = threadIdx.x;
  int sg = t >> 4, j = t & 15;
  int n = nb*16 + j;
  __shared__ float pm[16][17], pl[16][17];
  float m = -3.0e38f, l = 0.f;
  for (int i = 0; i < 16; ++i){
    int s = sg*16 + i;
    const float* rp = rowP + ((size_t)(b*256 + s)*NPAD + n)*2;
    float ms = rp[0], ls = rp[1];
    float mn = fmaxf(m, ms);
    l = l*__expf(m - mn) + ls*__expf(ms - mn);
    m = mn;
  }
  pm[sg][j] = m;
  pl[sg][j] = l;
  __syncthreads();
  if (sg == 0){
    float M = pm[0][j], L = pl[0][j];
    #pragma unroll
    for (int k = 1; k < 16; ++k){
      float ms = pm[k][j], ls = pl[k][j];
      float mn = fmaxf(M, ms);
      L = L*__expf(M - mn) + ls*__expf(ms - mn);
      M = mn;
    }
    mg[b*NPAD + n] = M;
    rz[b*NPAD + n] = 1.0f / L;
  }
}

// ---------------- kOut0: c-split (512 blocks, 3/CU), cached loads/stores
__global__ __launch_bounds__(512) void kOut0(const u16* __restrict__ Sg, const float* __restrict__ feat,
                                             const float* __restrict__ mg, u16* __restrict__ part){
  extern __shared__ char sm[];
  u16* Ep = (u16*)sm;                        // [NPAD][EP_STRIDE]
  u16* fN = (u16*)(sm + NPAD*EP_STRIDE*2);   // [128][FN_STRIDE]
  int b = blockIdx.x & 7, pr = (blockIdx.x >> 3) & 31, ch = (blockIdx.x >> 8) & 1;
  int t = threadIdx.x;
  const u16* Sb = Sg + (size_t)b*NPAD*HW;
  const float* featB = feat + (size_t)b*CDIM*HW;
  const float* mgB = mg + b*NPAD;
  int lane = t & 63, wv = t >> 6;
  int l15 = lane & 15, lk = (lane >> 4) & 3;
  int cstrip = wv*16;
  int rr = t >> 3, px8 = (t & 7)*8;
  f32x4 acc[10];
  #pragma unroll
  for (int nf = 0; nf < 10; ++nf) acc[nf] = (f32x4){0.f,0.f,0.f,0.f};
  for (int ck = 0; ck < 8; ++ck){
    int p0 = pr*512 + ck*64;
    #pragma unroll
    for (int ps = 0; ps < 3; ++ps){
      int rowi = ps*64 + rr;
      if (rowi < NPAD){
        u16x8 v = *(const u16x8*)&Sb[(size_t)rowi*HW + p0 + px8];
        float m = mgB[rowi];
        u16x8 o;
        #pragma unroll
        for (int j = 0; j < 8; ++j) o[j] = f2h(__expf(h2f(v[j]) - m));
        *(u16x8*)&Ep[rowi*EP_STRIDE + px8] = o;
      }
    }
    #pragma unroll
    for (int ps = 0; ps < 2; ++ps){
      int cl = ps*64 + rr;
      const float* g = featB + (size_t)(ch*128 + cl)*HW + p0 + px8;
      f32x4 v0 = *(const f32x4*)&g[0];
      f32x4 v1 = *(const f32x4*)&g[4];
      u16x8 o = {f2h(v0[0]), f2h(v0[1]), f2h(v0[2]), f2h(v0[3]),
                 f2h(v1[0]), f2h(v1[1]), f2h(v1[2]), f2h(v1[3])};
      *(u16x8*)&fN[cl*FN_STRIDE + px8] = o;
    }
    BAR_LDS();
    __builtin_amdgcn_s_setprio(1);
    #pragma unroll
    for (int kb = 0; kb < 2; ++kb){
      int ko = kb*32 + lk*8;
      f16x8 a0 = *(const f16x8*)&fN[(cstrip + l15)*FN_STRIDE + ko];
      #pragma unroll
      for (int nf = 0; nf < 10; ++nf){
        f16x8 bb = *(const f16x8*)&Ep[(nf*16 + l15)*EP_STRIDE + ko];
        acc[nf] = MFMA16F(a0, bb, acc[nf], 0, 0, 0);
      }
    }
    __builtin_amdgcn_s_setprio(0);
    BAR_LDS();
  }
  #pragma unroll
  for (int nf = 0; nf < 10; ++nf){
    #pragma unroll
    for (int r = 0; r < 4; ++r){
      int c = ch*128 + cstrip + lk*4 + r;
      int n = nf*16 + l15;
      part[((size_t)(b*32 + pr)*CDIM + c)*NPAD + n] = f2h(acc[nf][r]);
    }
  }
}

// ---------------- k4a: streaming reduce of part over 32 chunks, fold rZ -> combT
__global__ __launch_bounds__(256) void k4a(const u16* __restrict__ part, const float* __restrict__ rz,
                                           u16* __restrict__ combT){
  int b = blockIdx.x / 20, sub = blockIdx.x % 20, t = threadIdx.x;
  int idx8 = (sub*256 + t)*8;
  int c = idx8 / NPAD, n0 = idx8 % NPAD;
  const u16* base = part + (size_t)(b*32)*CDIM*NPAD + idx8;
  float a[8];
  #pragma unroll
  for (int j = 0; j < 8; ++j) a[j] = 0.f;
  for (int s = 0; s < 32; ++s){
    u16x8 v = *(const u16x8*)&base[(size_t)s*CDIM*NPAD];
    #pragma unroll
    for (int j = 0; j < 8; ++j) a[j] += h2f(v[j]);
  }
  const float* rzB = rz + b*NPAD + n0;
  #pragma unroll
  for (int j = 0; j < 8; ++j){
    combT[((size_t)(b*NPAD) + n0 + j)*CDIM + c] = f2h(a[j] * rzB[j]);
  }
}

// ---------------- k4b: out0[n][c] = cls + combT[n][:] @ WcF[c][:]  (MFMA, 80 n-rows/block)
__global__ __launch_bounds__(512) void k4b(const u16* __restrict__ combT, const u16* __restrict__ WcF,
                                           const float* __restrict__ cls, float* __restrict__ out0){
  extern __shared__ char sm[];
  u16* A = (u16*)sm;   // [80][CT_STRIDE]
  int b = blockIdx.x >> 1, nb = blockIdx.x & 1, t = threadIdx.x;
  const u16* cb = combT + (size_t)(b*NPAD + nb*80)*CDIM;
  #pragma unroll
  for (int it = 0; it < 10; ++it){
    int idx8 = (it*512 + t)*8;
    if (idx8 < 80*256){
      int row = idx8 >> 8, k0 = idx8 & 255;
      u16x8 v = *(const u16x8*)&cb[idx8];
      *(u16x8*)&A[row*CT_STRIDE + k0] = v;
    }
  }
  __syncthreads();
  int lane = t & 63, wv = t >> 6;
  int l15 = lane & 15, lk = (lane >> 4) & 3;
  int cstrip = wv*32;
  f32x4 acc[5][2];
  #pragma unroll
  for (int f = 0; f < 5; ++f)
    #pragma unroll
    for (int ct = 0; ct < 2; ++ct) acc[f][ct] = (f32x4){0.f,0.f,0.f,0.f};
  #pragma unroll
  for (int kb = 0; kb < 8; ++kb){
    int ko = kb*32 + lk*8;
    f16x8 b0 = *(const f16x8*)&WcF[(cstrip + l15)*CDIM + ko];
    f16x8 b1 = *(const f16x8*)&WcF[(cstrip + 16 + l15)*CDIM + ko];
    #pragma unroll
    for (int f = 0; f < 5; ++f){
      f16x8 af = *(const f16x8*)&A[(f*16 + l15)*CT_STRIDE + ko];
      acc[f][0] = MFMA16F(af, b0, acc[f][0], 0, 0, 0);
      acc[f][1] = MFMA16F(af, b1, acc[f][1], 0, 0, 0);
    }
  }
  #pragma unroll
  for (int f = 0; f < 5; ++f){
    #pragma unroll
    for (int r = 0; r < 4; ++r){
      int n = nb*80 + f*16 + lk*4 + r;
      if (n < NCLS){
        #pragma unroll
        for (int ct = 0; ct < 2; ++ct){
          int c = cstrip + ct*16 + l15;
          __builtin_nontemporal_store(cls[(size_t)(b*NCLS + n)*CDIM + c] + acc[f][ct][r],
                                      &out0[(size_t)(b*NCLS + n)*CDIM + c]);
        }
      }
    }
  }
}

extern "C" void kernel_launch(void* const* d_in, const int* in_sizes, int n_in,
                              void* d_out, int out_size, void* d_ws, size_t ws_size,
                              hipStream_t stream){
  (void)in_sizes; (void)n_in; (void)out_size; (void)ws_size;
  const float* cls  = (const float*)d_in[0];   // [8][150][256]
  const float* feat = (const float*)d_in[1];   // [8][256][16384]
  const float* Wc   = (const float*)d_in[2];   // [256][256]
  const float* Wf   = (const float*)d_in[3];   // [256][256]
  float* out0 = (float*)d_out;                 // [8][150][256]
  float* out1 = out0 + 8*NCLS*CDIM;            // [8][256][16384]
  char* ws = (char*)d_ws;
  u16*   clsF   = (u16*)(ws + WS_CLSF);
  u16*   clsWT  = (u16*)(ws + WS_CLSWT);
  float* mgv    = (float*)(ws + WS_MG);
  float* rzv    = (float*)(ws + WS_RZ);
  u16*   WcFv   = (u16*)(ws + WS_WCF);
  u16*   combTv = (u16*)(ws + WS_COMBT);
  float* rowPv  = (float*)(ws + WS_ROWP);
  u16*   partv  = (u16*)(ws + WS_PART);
  u16*   Sgp    = (u16*)(ws + WS_S);

  (void)hipFuncSetAttribute((const void*)kSO1, hipFuncAttributeMaxDynamicSharedMemorySize, SO_LDS);

  k0   <<<8*NPAD + 64, 256, 0, stream>>>(cls, Wf, Wc, clsF, clsWT, WcFv);
  kSO1 <<<256, 512, SO_LDS, stream>>>(feat, clsF, clsWT, Sgp, rowPv, out1);
  kComb<<<80, 256, 0, stream>>>(rowPv, mgv, rzv);
  kOut0<<<512, 512, O0_LDS, stream>>>(Sgp, feat, mgv, partv);
  k4a  <<<160, 256, 0, stream>>>(partv, rzv, combTv);
  k4b  <<<16, 512, 80*CT_STRIDE*2, stream>>>(combTv, WcFv, cls, out0);
}